// Round 12
// baseline (464.917 us; speedup 1.0000x reference)
//
#include <hip/hip_runtime.h>
#include <hip/hip_fp16.h>
#include <math.h>

#define CDIM 256
#define NE   1024
#define HW   4096            // 64*64
#define NB   16
#define ZQ_SIZE (NB*CDIM*HW) // 16777216

typedef unsigned short ushort_t;
typedef unsigned long long u64;
typedef __attribute__((ext_vector_type(8))) _Float16 f16x8;
typedef __attribute__((ext_vector_type(8))) unsigned short u16x8;
typedef __attribute__((ext_vector_type(4))) float f32x4;

#define AS1 __attribute__((address_space(1)))
#define AS3 __attribute__((address_space(3)))

// s-space margin (validated round 10, absmax 0): covers fl(zz+ee) rounding
// + final-sub rounding + 2*fp16-dot worst-case (~8.2e-5). Flagged tokens are
// exactly recomputed by the chunk fallback.
#define MARGIN 1.5e-4f

// ws layout (bytes) -- total 1,052,672 <= proven 1,052,928
#define WS_EE    0            // 1024 f32                (4096)
#define WS_PK    4096         // 65536 u64               (524288)
#define WS_ESWZ  528384       // 32 half-slabs x 16384 B (524288)
#define WS_NEEDED 1052672

// ---------------- helpers (validated rounds 1-10) ----------------
__device__ __forceinline__ float sq_nofma(float v) {
    float v2 = v * v;
    asm volatile("" : "+v"(v2));
    return v2;
}

template <typename F>
__device__ __forceinline__ float pairwise256_sq(F get) {
    float total = 0.0f;
    #pragma unroll
    for (int h = 0; h < 2; ++h) {
        float r[8];
        #pragma unroll
        for (int j = 0; j < 8; ++j) r[j] = sq_nofma(get(h * 128 + j));
        #pragma unroll
        for (int i = 8; i < 128; i += 8) {
            #pragma unroll
            for (int j = 0; j < 8; ++j) r[j] += sq_nofma(get(h * 128 + i + j));
        }
        float s = ((r[0] + r[1]) + (r[2] + r[3])) + ((r[4] + r[5]) + (r[6] + r[7]));
        total = (h == 0) ? s : (total + s);
    }
    return total;
}

template <typename F>
__device__ __forceinline__ float pairwise128_sq(F get) {
    float r[8];
    #pragma unroll
    for (int j = 0; j < 8; ++j) r[j] = sq_nofma(get(j));
    #pragma unroll
    for (int i = 8; i < 128; i += 8) {
        #pragma unroll
        for (int j = 0; j < 8; ++j) r[j] += sq_nofma(get(i + j));
    }
    return ((r[0] + r[1]) + (r[2] + r[3])) + ((r[4] + r[5]) + (r[6] + r[7]));
}

__device__ __forceinline__ ushort_t f2h(float v) {
    return __half_as_ushort(__float2half(v));   // v_cvt_f16_f32, RNE
}

// ||emb_j||^2 -> ws (legacy path only)
__global__ __launch_bounds__(256) void ee_kernel(const float* __restrict__ emb,
                                                 float* __restrict__ ee) {
    int j = blockIdx.x * 256 + threadIdx.x;
    const float* row = emb + (size_t)j * CDIM;
    ee[j] = pairwise256_sq([&](int i) { return row[i]; });
}

// merged: blocks 0..127 = emb fp32->fp16 fragment-major (ks-major halves);
// blocks 128..131 = ee. Half-slab t2 = s*2+ks at [t2*16384, +16384):
//   frag f = (code within chunk)>>4, at t2*16384 + f*1024 + (lg*16+lr)*16 + e*2
__global__ __launch_bounds__(256) void ecvt_kernel(const float* __restrict__ emb,
                                                   ushort_t* __restrict__ eswz,
                                                   float* __restrict__ ee) {
    if (blockIdx.x >= 128) {
        int j = (blockIdx.x - 128) * 256 + threadIdx.x;
        const float* row = emb + (size_t)j * CDIM;
        ee[j] = pairwise256_sq([&](int i) { return row[i]; });
        return;
    }
    int g = blockIdx.x * 256 + threadIdx.x;   // 32768 threads
    int s  = g >> 11;          // slab
    int r  = g & 2047;
    int cw = r >> 3;           // code within chunk 0..255
    int kg = r & 7;            // k-group of 8 within slab
    int chunk = s >> 2, kb = s & 3;
    int f  = cw >> 4, lr = cw & 15;
    int ks = kg >> 2, lg = kg & 3;

    const float* src = emb + (size_t)(chunk * 256 + cw) * CDIM + kb * 64 + kg * 8;
    float4 a = *reinterpret_cast<const float4*>(src);
    float4 b = *reinterpret_cast<const float4*>(src + 4);
    u16x8 p = { f2h(a.x), f2h(a.y), f2h(a.z), f2h(a.w),
                f2h(b.x), f2h(b.y), f2h(b.z), f2h(b.w) };
    size_t dst = (size_t)(s * 2 + ks) * 16384 + f * 1024 + (lg * 16 + lr) * 16;
    *reinterpret_cast<u16x8*>((char*)eswz + dst) = p;
}

// ---------------- main MFMA kernel: 512 thr, 8 waves, 64 tokens ----------------
// Barrier-free k-loop: wave wn owns codes wn*32..+31; per-wave E buffers
// (depth 4 x 2 KB), per-wave counted vmcnt(6). z frag-buffer read-only.
__global__ __launch_bounds__(512, 2) void vq_main(const float* __restrict__ z,
                                                  const float* __restrict__ emb,
                                                  const ushort_t* __restrict__ eswz,
                                                  const float* __restrict__ eew,
                                                  u64* __restrict__ pk,
                                                  float* __restrict__ out) {
    __shared__ __align__(16) char arena[104704];
    char*  zfB  = arena;                     // 32768: z fp16 fragment-major
    char*  ebuf = arena + 32768;             // 8 waves x 8192 (4 x 2 KB rotation)
    float* rd1  = (float*)(arena + 98304);   // [8][64]  (2048)
    int*   rj1  = (int*)  (arena + 100352);
    float* rd2  = (float*)(arena + 102400);
    int*   rbj  = (int*)  (arena + 104448);  // 64

    const int tid  = threadIdx.x;
    const int lane = tid & 63;
    const int wn   = tid >> 6;              // wave 0..7 (code group)
    const int b    = blockIdx.x >> 6;
    const int hw0  = (blockIdx.x & 63) << 6;
    const float* zb = z + (size_t)b * CDIM * HW + hw0;
    const int lr = lane & 15;
    const int lg = lane >> 4;
    const int laneoff = lane << 4;

    // per-wave DMA of the wave's 2 KB (frags 2wn,2wn+1) of half-slab t2
    auto issue_half = [&](int t2) {
        const char* gsrc = (const char*)eswz + (size_t)t2 * 16384 + (wn << 11) + laneoff;
        char* dstb = ebuf + (wn << 13) + ((t2 & 3) << 11);
        #pragma unroll
        for (int q = 0; q < 2; ++q)
            __builtin_amdgcn_global_load_lds(
                (const AS1 unsigned*)(gsrc + (q << 10)),
                (AS3 unsigned*)(dstb + (q << 10)), 16, 0, 0);
    };

    // ---- issue half-slabs 0..3 (hide latency under z staging) ----
    issue_half(0); issue_half(1); issue_half(2); issue_half(3);

    // ---- prologue: z -> fp16 frag-major ----
    {
        const int tok = lane;
        #pragma unroll
        for (int i = 0; i < 4; ++i) {
            int kg = (wn << 2) + i;          // 0..31
            int k0 = kg << 3;
            u16x8 p;
            #pragma unroll
            for (int e = 0; e < 8; ++e)
                p[e] = f2h(zb[(size_t)(k0 + e) * HW + tok]);
            int m = tok >> 4, lrr = tok & 15;
            int kb_ = kg >> 3, ks_ = (kg >> 2) & 1, lg_ = kg & 3;
            int off = (((kb_ * 2 + ks_) * 4 + m) << 10) + ((lg_ * 16 + lrr) << 4);
            *(u16x8*)(zfB + off) = p;
        }
    }
    asm volatile("s_waitcnt lgkmcnt(0)" ::: "memory");
    __builtin_amdgcn_s_barrier();            // zfB ready (E DMA still in flight)

    f32x4 acc[4][2];
    float sd1[4][4], sd2[4][4];
    int   sj1[4][4];
    #pragma unroll
    for (int m = 0; m < 4; ++m)
        #pragma unroll
        for (int r = 0; r < 4; ++r) { sd1[m][r] = INFINITY; sd2[m][r] = INFINITY; sj1[m][r] = NE; }

    auto epilogue = [&](int chunk) {   // s = ee - 2*dot (token-constant zz dropped)
        int code0 = (chunk << 8) + (wn << 5) + lr;
        float ee0 = eew[code0];
        float ee1 = eew[code0 + 16];
        #pragma unroll
        for (int m = 0; m < 4; ++m)
            #pragma unroll
            for (int r = 0; r < 4; ++r) {
                float d0 = ee0 - 2.0f * acc[m][0][r];
                float d1 = ee1 - 2.0f * acc[m][1][r];
                bool lt1 = d0 < sd1[m][r];
                bool lt2 = d0 < sd2[m][r];
                sd2[m][r] = lt1 ? sd1[m][r] : (lt2 ? d0 : sd2[m][r]);
                if (lt1) { sd1[m][r] = d0; sj1[m][r] = code0; }
                lt1 = d1 < sd1[m][r];
                lt2 = d1 < sd2[m][r];
                sd2[m][r] = lt1 ? sd1[m][r] : (lt2 ? d1 : sd2[m][r]);
                if (lt1) { sd1[m][r] = d1; sj1[m][r] = code0 + 16; }
            }
    };

#define K_STEP(T, NSTR)                                                        \
    do {                                                                       \
        asm volatile("s_waitcnt vmcnt(" NSTR ")" ::: "memory");                \
        const char* bufc_ = ebuf + (wn << 13) + (((T) & 3) << 11);             \
        f16x8 bh0_ = *(const f16x8*)(bufc_ + laneoff);                         \
        f16x8 bh1_ = *(const f16x8*)(bufc_ + 1024 + laneoff);                  \
        asm volatile("s_waitcnt lgkmcnt(0)" ::: "memory");                     \
        __builtin_amdgcn_sched_barrier(0);                                     \
        if ((T) + 4 < 32) issue_half((T) + 4);                                 \
        const int fb_ = (((((T) >> 1) & 3) * 2 + ((T) & 1)) << 2);             \
        f16x8 a0_ = *(const f16x8*)(zfB + ((fb_ + 0) << 10) + laneoff);        \
        f16x8 a1_ = *(const f16x8*)(zfB + ((fb_ + 1) << 10) + laneoff);        \
        f16x8 a2_ = *(const f16x8*)(zfB + ((fb_ + 2) << 10) + laneoff);        \
        f16x8 a3_ = *(const f16x8*)(zfB + ((fb_ + 3) << 10) + laneoff);        \
        acc[0][0] = __builtin_amdgcn_mfma_f32_16x16x32_f16(a0_, bh0_, acc[0][0], 0, 0, 0); \
        acc[0][1] = __builtin_amdgcn_mfma_f32_16x16x32_f16(a0_, bh1_, acc[0][1], 0, 0, 0); \
        acc[1][0] = __builtin_amdgcn_mfma_f32_16x16x32_f16(a1_, bh0_, acc[1][0], 0, 0, 0); \
        acc[1][1] = __builtin_amdgcn_mfma_f32_16x16x32_f16(a1_, bh1_, acc[1][1], 0, 0, 0); \
        acc[2][0] = __builtin_amdgcn_mfma_f32_16x16x32_f16(a2_, bh0_, acc[2][0], 0, 0, 0); \
        acc[2][1] = __builtin_amdgcn_mfma_f32_16x16x32_f16(a2_, bh1_, acc[2][1], 0, 0, 0); \
        acc[3][0] = __builtin_amdgcn_mfma_f32_16x16x32_f16(a3_, bh0_, acc[3][0], 0, 0, 0); \
        acc[3][1] = __builtin_amdgcn_mfma_f32_16x16x32_f16(a3_, bh1_, acc[3][1], 0, 0, 0); \
    } while (0)

    // ---- barrier-free k-loop: 32 half-steps, per-wave pipelined ----
    for (int t = 0; t < 28; ++t) {
        if ((t & 7) == 0) {
            #pragma unroll
            for (int m = 0; m < 4; ++m)
                #pragma unroll
                for (int n = 0; n < 2; ++n) acc[m][n] = (f32x4){0.f, 0.f, 0.f, 0.f};
        }
        K_STEP(t, "6");
        if ((t & 7) == 7) epilogue(t >> 3);
    }
    K_STEP(28, "6");
    K_STEP(29, "4");
    K_STEP(30, "2");
    K_STEP(31, "0");
    epilogue(3);
#undef K_STEP

    // ---- cross-lane top-2 merge over the 16 code-lanes ----
    #pragma unroll
    for (int off = 1; off <= 8; off <<= 1) {
        #pragma unroll
        for (int m = 0; m < 4; ++m)
            #pragma unroll
            for (int r = 0; r < 4; ++r) {
                float od1 = __shfl_xor(sd1[m][r], off);
                int   oj1 = __shfl_xor(sj1[m][r], off);
                float od2 = __shfl_xor(sd2[m][r], off);
                float nd2 = fminf(fmaxf(sd1[m][r], od1), fminf(sd2[m][r], od2));
                bool tk = (od1 < sd1[m][r]) || (od1 == sd1[m][r] && oj1 < sj1[m][r]);
                if (tk) { sd1[m][r] = od1; sj1[m][r] = oj1; }
                sd2[m][r] = nd2;
            }
    }
    if (lr == 0) {
        #pragma unroll
        for (int m = 0; m < 4; ++m)
            #pragma unroll
            for (int r = 0; r < 4; ++r) {
                int tok = m * 16 + lg * 4 + r;
                rd1[wn * 64 + tok] = sd1[m][r];
                rj1[wn * 64 + tok] = sj1[m][r];
                rd2[wn * 64 + tok] = sd2[m][r];
            }
    }
    __syncthreads();

    // ---- combine 8 code-groups, decide, emit idx / pk flag ----
    if (tid < 64) {
        float d1f = rd1[tid]; int j1f = rj1[tid]; float d2f = rd2[tid];
        #pragma unroll
        for (int w = 1; w < 8; ++w) {
            float od1 = rd1[w * 64 + tid];
            int   oj1 = rj1[w * 64 + tid];
            float od2 = rd2[w * 64 + tid];
            float nd2 = fminf(fmaxf(d1f, od1), fminf(d2f, od2));
            bool tk = (od1 < d1f) || (od1 == d1f && oj1 < j1f);
            if (tk) { d1f = od1; j1f = oj1; }
            d2f = nd2;
        }
        rbj[tid] = j1f;
        int gtok = b * HW + hw0 + tid;
        out[(size_t)ZQ_SIZE + gtok] = (float)j1f;
        pk[gtok] = (d2f - d1f > MARGIN) ? 0ull : ~0ull;
    }
    __syncthreads();

    // ---- z_q: gather emb rows -> LDS -> coalesced NCHW ----
    float* zq_st = (float*)arena;   // [64][260] = 66560 B (rbj at 104448 safe)
    {
        int row = tid >> 3, sub = tid & 7;
        int j = rbj[row];
        const float* er = emb + (size_t)j * CDIM;
        #pragma unroll
        for (int i = 0; i < 8; ++i) {
            int c = (sub << 2) + (i << 5);
            float4 v = *reinterpret_cast<const float4*>(er + c);
            *reinterpret_cast<float4*>(&zq_st[row * 260 + c]) = v;
        }
    }
    __syncthreads();
    {
        int tok = tid & 63, cg = tid >> 6;
        float* ob = out + (size_t)b * CDIM * HW + hw0 + tok;
        #pragma unroll 4
        for (int i = 0; i < 32; ++i) {
            int c = (cg << 5) + i;
            ob[(size_t)c * HW] = zq_st[tok * 260 + c];
        }
    }
}

// ---------------- chunk-parallel exact fallback ----------------
// Grid = 16 chunks x 32 token-stripes. Each block stages one 64-code chunk,
// scans pk!=0 tokens in its stripe, recomputes the exact round-1 chain, and
// atomicMin's packed (d,j) into pk.
__global__ __launch_bounds__(512) void vq_fb_chunk(const float* __restrict__ z,
                                                   const float* __restrict__ emb,
                                                   const float* __restrict__ eew,
                                                   u64* __restrict__ pk) {
    __shared__ __align__(16) float elds[64 * 260];
    __shared__ float zsh[8][256];

    const int tid  = threadIdx.x;
    const int lane = tid & 63;
    const int wv   = tid >> 6;
    const int c      = blockIdx.x & 15;
    const int stripe = blockIdx.x >> 4;    // 0..31

    {   // stage chunk c: 64 codes x 256 dims
        int row = tid >> 3, sub = tid & 7;
        #pragma unroll
        for (int i = 0; i < 8; ++i) {
            int col = (sub << 2) + (i << 5);
            float4 v = *reinterpret_cast<const float4*>(
                &emb[(size_t)(c * 64 + row) * CDIM + col]);
            *reinterpret_cast<float4*>(&elds[row * 260 + col]) = v;
        }
    }
    __syncthreads();

    const int tbase = stripe * 2048 + wv * 256;
    const int code  = c * 64 + lane;
    const float eev = eew[code];

    for (int i = 0; i < 4; ++i) {
        int t = tbase + i * 64 + lane;
        u64 v = pk[t];                              // coalesced flag scan
        u64 msk = __ballot(v != 0ull);
        while (msk) {
            int bidx = __ffsll((long long)msk) - 1;
            msk &= msk - 1;
            int gt  = tbase + i * 64 + bidx;
            int tb  = gt >> 12, thw = gt & 4095;
            // stage z row (wave-local)
            #pragma unroll
            for (int q = 0; q < 4; ++q)
                zsh[wv][q * 64 + lane] =
                    z[(size_t)tb * CDIM * HW + (size_t)(q * 64 + lane) * HW + thw];
            asm volatile("s_waitcnt lgkmcnt(0)" ::: "memory");
            __builtin_amdgcn_sched_barrier(0);
            // exact numpy-pairwise zz (2 lanes, combine)
            float zzh = 0.0f;
            if (lane < 2)
                zzh = pairwise128_sq([&](int k) { return zsh[wv][lane * 128 + k]; });
            float zz = __shfl(zzh, 0) + __shfl(zzh, 1);
            // exact fp32 fmaf dot, ascending k (round-1 chain)
            float acc = 0.0f;
            #pragma unroll 8
            for (int kq = 0; kq < 64; ++kq) {
                float4 ev = *reinterpret_cast<const float4*>(&elds[lane * 260 + kq * 4]);
                float4 zv = *reinterpret_cast<const float4*>(&zsh[wv][kq * 4]);
                acc = fmaf(zv.x, ev.x, acc);
                acc = fmaf(zv.y, ev.y, acc);
                acc = fmaf(zv.z, ev.z, acc);
                acc = fmaf(zv.w, ev.w, acc);
            }
            float t1 = zz + eev;
            float d  = t1 - 2.0f * acc;             // d > 0 here (zz ~ 256)
            u64 key = ((u64)__float_as_uint(d) << 32) | (unsigned)code;
            atomicMin(&pk[gt], key);
        }
    }
}

// finalize: unpack winners, overwrite idx + z_q for flagged tokens
__global__ __launch_bounds__(256) void vq_fb_fin(const float* __restrict__ emb,
                                                 const u64* __restrict__ pk,
                                                 float* __restrict__ out) {
    int t = blockIdx.x * 256 + threadIdx.x;   // grid 256 -> all 65536 tokens
    u64 v = pk[t];
    if (v == 0ull) return;
    int j = (int)(v & 0xFFFFFFFFull);
    out[(size_t)ZQ_SIZE + t] = (float)j;
    int tb = t >> 12, thw = t & 4095;
    const float* er = emb + (size_t)j * CDIM;
    float* ob = out + (size_t)tb * CDIM * HW + thw;
    #pragma unroll 4
    for (int cc = 0; cc < CDIM; ++cc)
        ob[(size_t)cc * HW] = er[cc];
}

// ---------------- legacy round-1 kernel (only if ws too small) ----------------
#define BM 32
#define BN 256
#define BK 16
__global__ __launch_bounds__(256, 3) void vq_legacy(const float* __restrict__ z,
                                                    const float* __restrict__ emb,
                                                    const float* __restrict__ ee,
                                                    float* __restrict__ out) {
    __shared__ float zs[CDIM][BM];
    __shared__ float es[BK][BN];
    __shared__ float ees[BN];
    __shared__ float zzs[BM];
    __shared__ float red_d[4][BM];
    __shared__ int   red_j[4][BM];
    __shared__ int   bestj_s[BM];

    const int tid = threadIdx.x;
    const int b   = blockIdx.x >> 7;
    const int hw0 = (blockIdx.x & 127) << 5;
    const int ti  = tid & 7;
    const int tj  = tid >> 3;
    const int tm0 = ti << 2;
    const int jc0 = tj << 3;
    {
        const float* zb = z + (size_t)b * CDIM * HW + hw0;
        #pragma unroll
        for (int r = 0; r < 8; ++r) {
            int f4 = (r << 8) + tid;
            int c  = f4 >> 3;
            int t4 = (f4 & 7) << 2;
            float4 v = *reinterpret_cast<const float4*>(zb + (size_t)c * HW + t4);
            *reinterpret_cast<float4*>(&zs[c][t4]) = v;
        }
    }
    __syncthreads();
    if (tid < BM) zzs[tid] = pairwise256_sq([&](int i) { return zs[i][tid]; });
    __syncthreads();
    float bd[4]; int bj[4];
    #pragma unroll
    for (int i = 0; i < 4; ++i) { bd[i] = INFINITY; bj[i] = NE; }
    for (int jt = 0; jt < NE / BN; ++jt) {
        const int j0 = jt * BN;
        float acc[4][8];
        #pragma unroll
        for (int i = 0; i < 4; ++i)
            #pragma unroll
            for (int jj = 0; jj < 8; ++jj) acc[i][jj] = 0.0f;
        for (int kt = 0; kt < CDIM / BK; ++kt) {
            __syncthreads();
            #pragma unroll
            for (int r = 0; r < 4; ++r) {
                int f4 = (r << 8) + tid;
                int jj = f4 >> 2;
                int c4 = (f4 & 3) << 2;
                float4 v = *reinterpret_cast<const float4*>(
                    emb + (size_t)(j0 + jj) * CDIM + kt * BK + c4);
                es[c4 + 0][jj] = v.x; es[c4 + 1][jj] = v.y;
                es[c4 + 2][jj] = v.z; es[c4 + 3][jj] = v.w;
            }
            if (kt == 0 && tid < BN) ees[tid] = ee[j0 + tid];
            __syncthreads();
            #pragma unroll
            for (int k = 0; k < BK; ++k) {
                float4 av  = *reinterpret_cast<const float4*>(&zs[kt * BK + k][tm0]);
                float4 bv0 = *reinterpret_cast<const float4*>(&es[k][jc0]);
                float4 bv1 = *reinterpret_cast<const float4*>(&es[k][jc0 + 4]);
                float bb[8] = {bv0.x, bv0.y, bv0.z, bv0.w, bv1.x, bv1.y, bv1.z, bv1.w};
                #pragma unroll
                for (int jj = 0; jj < 8; ++jj) {
                    acc[0][jj] = fmaf(av.x, bb[jj], acc[0][jj]);
                    acc[1][jj] = fmaf(av.y, bb[jj], acc[1][jj]);
                    acc[2][jj] = fmaf(av.z, bb[jj], acc[2][jj]);
                    acc[3][jj] = fmaf(av.w, bb[jj], acc[3][jj]);
                }
            }
        }
        #pragma unroll
        for (int i = 0; i < 4; ++i) {
            float zzv = zzs[tm0 + i];
            #pragma unroll
            for (int jj = 0; jj < 8; ++jj) {
                float t1 = zzv + ees[jc0 + jj];
                float d  = t1 - 2.0f * acc[i][jj];
                if (d < bd[i]) { bd[i] = d; bj[i] = j0 + jc0 + jj; }
            }
        }
    }
    #pragma unroll
    for (int off = 8; off <= 32; off <<= 1) {
        #pragma unroll
        for (int i = 0; i < 4; ++i) {
            float od = __shfl_xor(bd[i], off);
            int   oj = __shfl_xor(bj[i], off);
            if (od < bd[i] || (od == bd[i] && oj < bj[i])) { bd[i] = od; bj[i] = oj; }
        }
    }
    {
        const int lane = tid & 63;
        const int w    = tid >> 6;
        if (lane < 8) {
            #pragma unroll
            for (int i = 0; i < 4; ++i) {
                red_d[w][lane * 4 + i] = bd[i];
                red_j[w][lane * 4 + i] = bj[i];
            }
        }
    }
    __syncthreads();
    if (tid < BM) {
        float d = red_d[0][tid]; int j = red_j[0][tid];
        #pragma unroll
        for (int w2 = 1; w2 < 4; ++w2) {
            float od = red_d[w2][tid]; int oj = red_j[w2][tid];
            if (od < d || (od == d && oj < j)) { d = od; j = oj; }
        }
        bestj_s[tid] = j;
        out[(size_t)ZQ_SIZE + (size_t)b * HW + hw0 + tid] = (float)j;
    }
    __syncthreads();
    {
        const int t  = tid & 31;
        const int c0 = tid >> 5;
        const int jb = bestj_s[t];
        const float* er = emb + (size_t)jb * CDIM;
        float* ob = out + (size_t)b * CDIM * HW + hw0 + t;
        #pragma unroll
        for (int c = c0; c < CDIM; c += 8) ob[(size_t)c * HW] = er[c];
    }
}

extern "C" void kernel_launch(void* const* d_in, const int* in_sizes, int n_in,
                              void* d_out, int out_size, void* d_ws, size_t ws_size,
                              hipStream_t stream) {
    const float* z   = (const float*)d_in[0];
    const float* emb = (const float*)d_in[1];
    float* out = (float*)d_out;
    char*  ws  = (char*)d_ws;

    float*    ee   = (float*)(ws + WS_EE);
    u64*      pk   = (u64*)  (ws + WS_PK);
    ushort_t* eswz = (ushort_t*)(ws + WS_ESWZ);

    if (ws_size >= (size_t)WS_NEEDED) {
        ecvt_kernel<<<dim3(132), dim3(256), 0, stream>>>(emb, eswz, ee);
        vq_main<<<dim3((NB * HW) / 64), dim3(512), 0, stream>>>(z, emb, eswz, ee,
                                                                pk, out);
        vq_fb_chunk<<<dim3(512), dim3(512), 0, stream>>>(z, emb, ee, pk);
        vq_fb_fin<<<dim3(256), dim3(256), 0, stream>>>(emb, pk, out);
    } else {
        ee_kernel<<<dim3(NE / 256), dim3(256), 0, stream>>>(emb, ee);
        vq_legacy<<<dim3((NB * HW) / BM), dim3(256), 0, stream>>>(z, emb, ee, out);
    }
}

// Round 13
// 392.359 us; speedup vs baseline: 1.1849x; 1.1849x over previous
//
#include <hip/hip_runtime.h>
#include <hip/hip_fp16.h>
#include <math.h>

#define CDIM 256
#define NE   1024
#define HW   4096            // 64*64
#define NB   16
#define ZQ_SIZE (NB*CDIM*HW) // 16777216

typedef unsigned short ushort_t;
typedef __attribute__((ext_vector_type(8))) _Float16 f16x8;
typedef __attribute__((ext_vector_type(8))) unsigned short u16x8;
typedef __attribute__((ext_vector_type(4))) float f32x4;

#define AS1 __attribute__((address_space(1)))
#define AS3 __attribute__((address_space(3)))

// d-space margin, validated rounds 6-8 (absmax 0 x3): covers fp16 1-pass
// dot error (sigma ~5.2e-6, 11+ sigma) incl. fp32 grid slop. Flagged tokens
// (~0.8%) are exactly recomputed by the wave fallback.
#define MARGIN 6.0e-5f

// ws layout (bytes) -- round-10 proven layout
#define WS_EE    0           // 1024 f32
#define WS_ZZ    4096        // 65536 f32
#define WS_CNT   266240      // 1 int (+pad)
#define WS_LIST  266496      // 65536 int
#define WS_ESWZ  528640      // 32 half-slabs x 16384 B fp16 fragment-major
#define WS_NEEDED 1052928

// ---------------- helpers (validated rounds 1-12) ----------------
__device__ __forceinline__ float sq_nofma(float v) {
    float v2 = v * v;
    asm volatile("" : "+v"(v2));
    return v2;
}

template <typename F>
__device__ __forceinline__ float pairwise256_sq(F get) {
    float total = 0.0f;
    #pragma unroll
    for (int h = 0; h < 2; ++h) {
        float r[8];
        #pragma unroll
        for (int j = 0; j < 8; ++j) r[j] = sq_nofma(get(h * 128 + j));
        #pragma unroll
        for (int i = 8; i < 128; i += 8) {
            #pragma unroll
            for (int j = 0; j < 8; ++j) r[j] += sq_nofma(get(h * 128 + i + j));
        }
        float s = ((r[0] + r[1]) + (r[2] + r[3])) + ((r[4] + r[5]) + (r[6] + r[7]));
        total = (h == 0) ? s : (total + s);
    }
    return total;
}

template <typename F>
__device__ __forceinline__ float pairwise128_sq(F get) {
    float r[8];
    #pragma unroll
    for (int j = 0; j < 8; ++j) r[j] = sq_nofma(get(j));
    #pragma unroll
    for (int i = 8; i < 128; i += 8) {
        #pragma unroll
        for (int j = 0; j < 8; ++j) r[j] += sq_nofma(get(i + j));
    }
    return ((r[0] + r[1]) + (r[2] + r[3])) + ((r[4] + r[5]) + (r[6] + r[7]));
}

__device__ __forceinline__ ushort_t f2h(float v) {
    return __half_as_ushort(__float2half(v));   // v_cvt_f16_f32, RNE
}

// ||emb_j||^2 -> ws (legacy path only)
__global__ __launch_bounds__(256) void ee_kernel(const float* __restrict__ emb,
                                                 float* __restrict__ ee) {
    int j = blockIdx.x * 256 + threadIdx.x;
    const float* row = emb + (size_t)j * CDIM;
    ee[j] = pairwise256_sq([&](int i) { return row[i]; });
}

// merged: blocks 0..127 = emb fp32->fp16 fragment-major (ks-major halves);
// blocks 128..131 = ee (+ cnt zero). Half-slab t2 = s*2+ks at [t2*16384):
//   frag f = (code within chunk)>>4, at t2*16384 + f*1024 + (lg*16+lr)*16 + e*2
__global__ __launch_bounds__(256) void ecvt_kernel(const float* __restrict__ emb,
                                                   ushort_t* __restrict__ eswz,
                                                   float* __restrict__ ee,
                                                   int* __restrict__ cnt) {
    if (blockIdx.x >= 128) {
        if (blockIdx.x == 128 && threadIdx.x == 0) *cnt = 0;
        int j = (blockIdx.x - 128) * 256 + threadIdx.x;
        const float* row = emb + (size_t)j * CDIM;
        ee[j] = pairwise256_sq([&](int i) { return row[i]; });
        return;
    }
    int g = blockIdx.x * 256 + threadIdx.x;   // 32768 threads
    int s  = g >> 11;          // slab
    int r  = g & 2047;
    int cw = r >> 3;           // code within chunk 0..255
    int kg = r & 7;            // k-group of 8 within slab
    int chunk = s >> 2, kb = s & 3;
    int f  = cw >> 4, lr = cw & 15;
    int ks = kg >> 2, lg = kg & 3;

    const float* src = emb + (size_t)(chunk * 256 + cw) * CDIM + kb * 64 + kg * 8;
    float4 a = *reinterpret_cast<const float4*>(src);
    float4 b = *reinterpret_cast<const float4*>(src + 4);
    u16x8 p = { f2h(a.x), f2h(a.y), f2h(a.z), f2h(a.w),
                f2h(b.x), f2h(b.y), f2h(b.z), f2h(b.w) };
    size_t dst = (size_t)(s * 2 + ks) * 16384 + f * 1024 + (lg * 16 + lr) * 16;
    *reinterpret_cast<u16x8*>((char*)eswz + dst) = p;
}

// ---------------- main MFMA kernel: 512 thr, 8 waves, 64 tokens ----------------
// Barrier-free k-loop; per-wave depth-2 E buffers (4 KB/wave), per-wave
// counted vmcnt(2). LDS 66.8 KB -> 2 blocks/CU. d-space decide, MARGIN 6e-5.
__global__ __launch_bounds__(512, 4) void vq_main(const float* __restrict__ z,
                                                  const float* __restrict__ emb,
                                                  const ushort_t* __restrict__ eswz,
                                                  const float* __restrict__ eew,
                                                  float* __restrict__ zzw,
                                                  int* __restrict__ cnt,
                                                  int* __restrict__ list,
                                                  float* __restrict__ out) {
    __shared__ __align__(16) char arena[66816];
    char*  zfB  = arena;                     // 32768: z fp16 fragment-major
    char*  ebuf = arena + 32768;             // 8 waves x 4096 (2 x 2 KB rotation)
    float* zzp  = (float*)(arena + 65536);   // 64x2 f32 halves (512 B)
    int*   rbj  = (int*)  (arena + 66560);   // 64 ints
    // post-loop aliases (ebuf dead after k-loop + barrier):
    float* rd1  = (float*)(arena + 32768);   // [8][64]
    int*   rj1  = (int*)  (arena + 34816);
    float* rd2  = (float*)(arena + 36864);

    const int tid  = threadIdx.x;
    const int lane = tid & 63;
    const int wn   = tid >> 6;              // wave 0..7 (code group)
    const int b    = blockIdx.x >> 6;
    const int hw0  = (blockIdx.x & 63) << 6;
    const float* zb = z + (size_t)b * CDIM * HW + hw0;
    const int lr = lane & 15;
    const int lg = lane >> 4;
    const int laneoff = lane << 4;

    // per-wave DMA of the wave's 2 KB (frags 2wn,2wn+1) of half-slab t2
    auto issue_half = [&](int t2) {
        const char* gsrc = (const char*)eswz + (size_t)t2 * 16384 + (wn << 11) + laneoff;
        char* dstb = ebuf + (wn << 12) + ((t2 & 1) << 11);
        #pragma unroll
        for (int q = 0; q < 2; ++q)
            __builtin_amdgcn_global_load_lds(
                (const AS1 unsigned*)(gsrc + (q << 10)),
                (AS3 unsigned*)(dstb + (q << 10)), 16, 0, 0);
    };

    // ---- issue half-slabs 0,1 (latency hides under z staging) ----
    issue_half(0);
    issue_half(1);

    // ---- prologue: z -> fp16 frag-major + zz halves ----
    {
        const int tok = lane;
        #pragma unroll
        for (int i = 0; i < 4; ++i) {
            int kg = (wn << 2) + i;          // 0..31
            int k0 = kg << 3;
            u16x8 p;
            #pragma unroll
            for (int e = 0; e < 8; ++e)
                p[e] = f2h(zb[(size_t)(k0 + e) * HW + tok]);
            int m = tok >> 4, lrr = tok & 15;
            int kb_ = kg >> 3, ks_ = (kg >> 2) & 1, lg_ = kg & 3;
            int off = (((kb_ * 2 + ks_) * 4 + m) << 10) + ((lg_ * 16 + lrr) << 4);
            *(u16x8*)(zfB + off) = p;
        }
    }
    if (tid < 128) {   // exact numpy-pairwise halves
        int tok = tid >> 1, h = tid & 1;
        zzp[tok * 2 + h] = pairwise128_sq([&](int i) {
            return zb[(size_t)(h * 128 + i) * HW + tok];
        });
    }
    asm volatile("s_waitcnt lgkmcnt(0)" ::: "memory");
    __builtin_amdgcn_s_barrier();            // zfB + zzp ready (E DMA in flight)

    f32x4 acc[4][2];
    float sd1[4][4], sd2[4][4];
    int   sj1[4][4];
    #pragma unroll
    for (int m = 0; m < 4; ++m)
        #pragma unroll
        for (int r = 0; r < 4; ++r) { sd1[m][r] = INFINITY; sd2[m][r] = INFINITY; sj1[m][r] = NE; }

    // chunk epilogue: d = fl(fl(zz+ee) - fl(2*dot)) (validated chain), top-2
    auto epilogue = [&](int chunk) {
        int code0 = (chunk << 8) + (wn << 5) + lr;
        float ee0 = eew[code0];
        float ee1 = eew[code0 + 16];
        #pragma unroll
        for (int m = 0; m < 4; ++m)
            #pragma unroll
            for (int r = 0; r < 4; ++r) {
                int tk = m * 16 + lg * 4 + r;
                float2 zp = *reinterpret_cast<const float2*>(&zzp[2 * tk]);
                float zzv = zp.x + zp.y;
                float d0 = (zzv + ee0) - 2.0f * acc[m][0][r];
                float d1 = (zzv + ee1) - 2.0f * acc[m][1][r];
                bool lt1 = d0 < sd1[m][r];
                bool lt2 = d0 < sd2[m][r];
                sd2[m][r] = lt1 ? sd1[m][r] : (lt2 ? d0 : sd2[m][r]);
                if (lt1) { sd1[m][r] = d0; sj1[m][r] = code0; }
                lt1 = d1 < sd1[m][r];
                lt2 = d1 < sd2[m][r];
                sd2[m][r] = lt1 ? sd1[m][r] : (lt2 ? d1 : sd2[m][r]);
                if (lt1) { sd1[m][r] = d1; sj1[m][r] = code0 + 16; }
            }
    };

#define K_STEP(T, NSTR)                                                        \
    do {                                                                       \
        asm volatile("s_waitcnt vmcnt(" NSTR ")" ::: "memory");                \
        const char* bufc_ = ebuf + (wn << 12) + (((T) & 1) << 11);             \
        f16x8 bh0_ = *(const f16x8*)(bufc_ + laneoff);                         \
        f16x8 bh1_ = *(const f16x8*)(bufc_ + 1024 + laneoff);                  \
        asm volatile("s_waitcnt lgkmcnt(0)" ::: "memory");                     \
        __builtin_amdgcn_sched_barrier(0);                                     \
        if ((T) + 2 < 32) issue_half((T) + 2);                                 \
        const int fb_ = (((((T) >> 1) & 3) * 2 + ((T) & 1)) << 2);             \
        f16x8 a0_ = *(const f16x8*)(zfB + ((fb_ + 0) << 10) + laneoff);        \
        f16x8 a1_ = *(const f16x8*)(zfB + ((fb_ + 1) << 10) + laneoff);        \
        f16x8 a2_ = *(const f16x8*)(zfB + ((fb_ + 2) << 10) + laneoff);        \
        f16x8 a3_ = *(const f16x8*)(zfB + ((fb_ + 3) << 10) + laneoff);        \
        acc[0][0] = __builtin_amdgcn_mfma_f32_16x16x32_f16(a0_, bh0_, acc[0][0], 0, 0, 0); \
        acc[0][1] = __builtin_amdgcn_mfma_f32_16x16x32_f16(a0_, bh1_, acc[0][1], 0, 0, 0); \
        acc[1][0] = __builtin_amdgcn_mfma_f32_16x16x32_f16(a1_, bh0_, acc[1][0], 0, 0, 0); \
        acc[1][1] = __builtin_amdgcn_mfma_f32_16x16x32_f16(a1_, bh1_, acc[1][1], 0, 0, 0); \
        acc[2][0] = __builtin_amdgcn_mfma_f32_16x16x32_f16(a2_, bh0_, acc[2][0], 0, 0, 0); \
        acc[2][1] = __builtin_amdgcn_mfma_f32_16x16x32_f16(a2_, bh1_, acc[2][1], 0, 0, 0); \
        acc[3][0] = __builtin_amdgcn_mfma_f32_16x16x32_f16(a3_, bh0_, acc[3][0], 0, 0, 0); \
        acc[3][1] = __builtin_amdgcn_mfma_f32_16x16x32_f16(a3_, bh1_, acc[3][1], 0, 0, 0); \
    } while (0)

    // ---- barrier-free k-loop: 32 half-steps, per-wave depth-2 pipeline ----
    for (int t = 0; t < 31; ++t) {
        if ((t & 7) == 0) {
            #pragma unroll
            for (int m = 0; m < 4; ++m)
                #pragma unroll
                for (int n = 0; n < 2; ++n) acc[m][n] = (f32x4){0.f, 0.f, 0.f, 0.f};
        }
        K_STEP(t, "2");
        if ((t & 7) == 7) epilogue(t >> 3);
    }
    K_STEP(31, "0");
    epilogue(3);
#undef K_STEP

    // ---- cross-lane top-2 merge over the 16 code-lanes ----
    #pragma unroll
    for (int off = 1; off <= 8; off <<= 1) {
        #pragma unroll
        for (int m = 0; m < 4; ++m)
            #pragma unroll
            for (int r = 0; r < 4; ++r) {
                float od1 = __shfl_xor(sd1[m][r], off);
                int   oj1 = __shfl_xor(sj1[m][r], off);
                float od2 = __shfl_xor(sd2[m][r], off);
                float nd2 = fminf(fmaxf(sd1[m][r], od1), fminf(sd2[m][r], od2));
                bool tk = (od1 < sd1[m][r]) || (od1 == sd1[m][r] && oj1 < sj1[m][r]);
                if (tk) { sd1[m][r] = od1; sj1[m][r] = oj1; }
                sd2[m][r] = nd2;
            }
    }
    __syncthreads();   // all waves done reading ebuf -> safe to alias rd1/rj1/rd2
    if (lr == 0) {
        #pragma unroll
        for (int m = 0; m < 4; ++m)
            #pragma unroll
            for (int r = 0; r < 4; ++r) {
                int tok = m * 16 + lg * 4 + r;
                rd1[wn * 64 + tok] = sd1[m][r];
                rj1[wn * 64 + tok] = sj1[m][r];
                rd2[wn * 64 + tok] = sd2[m][r];
            }
    }
    __syncthreads();

    // ---- combine 8 code-groups, decide, emit idx / flag / zz ----
    if (tid < 64) {
        float d1f = rd1[tid]; int j1f = rj1[tid]; float d2f = rd2[tid];
        #pragma unroll
        for (int w = 1; w < 8; ++w) {
            float od1 = rd1[w * 64 + tid];
            int   oj1 = rj1[w * 64 + tid];
            float od2 = rd2[w * 64 + tid];
            float nd2 = fminf(fmaxf(d1f, od1), fminf(d2f, od2));
            bool tk = (od1 < d1f) || (od1 == d1f && oj1 < j1f);
            if (tk) { d1f = od1; j1f = oj1; }
            d2f = nd2;
        }
        rbj[tid] = j1f;
        int gtok = b * HW + hw0 + tid;
        out[(size_t)ZQ_SIZE + gtok] = (float)j1f;
        zzw[gtok] = zzp[2 * tid] + zzp[2 * tid + 1];
        if (!(d2f - d1f > MARGIN)) {
            int slot = atomicAdd(cnt, 1);
            list[slot] = gtok;
        }
    }
    __syncthreads();

    // ---- z_q: gather emb rows -> LDS -> coalesced NCHW ----
    float* zq_st = (float*)arena;   // [64][260] = 66560 B (rbj at 66560 safe)
    {
        int row = tid >> 3, sub = tid & 7;
        int j = rbj[row];
        const float* er = emb + (size_t)j * CDIM;
        #pragma unroll
        for (int i = 0; i < 8; ++i) {
            int c = (sub << 2) + (i << 5);
            float4 v = *reinterpret_cast<const float4*>(er + c);
            *reinterpret_cast<float4*>(&zq_st[row * 260 + c]) = v;
        }
    }
    __syncthreads();
    {
        int tok = tid & 63, cg = tid >> 6;
        float* ob = out + (size_t)b * CDIM * HW + hw0 + tok;
        #pragma unroll 4
        for (int i = 0; i < 32; ++i) {
            int c = (cg << 5) + i;
            ob[(size_t)c * HW] = zq_st[tok * 260 + c];
        }
    }
}

// ---------------- exact fp32 fallback: one wave per token-pair ----------------
// emb read directly from L2 (1 MB, resident); z rows staged per-wave in LDS
// and broadcast-read; round-1-validated fmaf chain; finalize inline.
__global__ __launch_bounds__(512) void vq_fallback(const float* __restrict__ z,
                                                   const float* __restrict__ emb,
                                                   const float* __restrict__ eew,
                                                   const float* __restrict__ zzw,
                                                   const int* __restrict__ cnt,
                                                   const int* __restrict__ list,
                                                   float* __restrict__ out) {
    __shared__ float zrow[8][2][256];   // per-wave pair buffers (16 KB)
    const int tid  = threadIdx.x;
    const int lane = tid & 63;
    const int wv   = tid >> 6;
    const int gw   = blockIdx.x * 8 + wv;   // 0..2047
    const int nt   = *cnt;

    for (int base = gw * 2; base < nt; base += 4096) {
        int gt0 = list[base];
        int gt1 = (base + 1 < nt) ? list[base + 1] : -1;
        int tb0 = gt0 >> 12, th0 = gt0 & 4095;
        int tb1 = (gt1 >= 0) ? (gt1 >> 12) : 0;
        int th1 = (gt1 >= 0) ? (gt1 & 4095) : 0;
        #pragma unroll
        for (int q = 0; q < 4; ++q) {
            zrow[wv][0][q * 64 + lane] =
                z[(size_t)tb0 * CDIM * HW + (size_t)(q * 64 + lane) * HW + th0];
            if (gt1 >= 0)
                zrow[wv][1][q * 64 + lane] =
                    z[(size_t)tb1 * CDIM * HW + (size_t)(q * 64 + lane) * HW + th1];
        }
        float zz0 = zzw[gt0];
        float zz1 = (gt1 >= 0) ? zzw[gt1] : 0.0f;
        asm volatile("s_waitcnt vmcnt(0) lgkmcnt(0)" ::: "memory");
        __builtin_amdgcn_sched_barrier(0);

        float da = INFINITY, db = INFINITY;
        int   ja = NE,       jb = NE;
        for (int g = 0; g < 16; ++g) {
            int j = g * 64 + lane;
            const float* er = emb + (size_t)j * CDIM;
            float a0 = 0.0f, a1 = 0.0f;
            #pragma unroll 8
            for (int kq = 0; kq < 64; ++kq) {
                float4 ev = *reinterpret_cast<const float4*>(er + kq * 4);
                float4 z0 = *reinterpret_cast<const float4*>(&zrow[wv][0][kq * 4]);
                float4 z1 = *reinterpret_cast<const float4*>(&zrow[wv][1][kq * 4]);
                a0 = fmaf(z0.x, ev.x, a0); a0 = fmaf(z0.y, ev.y, a0);
                a0 = fmaf(z0.z, ev.z, a0); a0 = fmaf(z0.w, ev.w, a0);
                a1 = fmaf(z1.x, ev.x, a1); a1 = fmaf(z1.y, ev.y, a1);
                a1 = fmaf(z1.z, ev.z, a1); a1 = fmaf(z1.w, ev.w, a1);
            }
            float eev = eew[j];
            float d0 = (zz0 + eev) - 2.0f * a0;
            float d1 = (zz1 + eev) - 2.0f * a1;
            if (d0 < da) { da = d0; ja = j; }      // per-lane j ascends: strict <
            if (d1 < db) { db = d1; jb = j; }
        }
        #pragma unroll
        for (int off = 1; off <= 32; off <<= 1) {   // lexicographic reduce
            float oda = __shfl_xor(da, off); int oja = __shfl_xor(ja, off);
            if (oda < da || (oda == da && oja < ja)) { da = oda; ja = oja; }
            float odb = __shfl_xor(db, off); int ojb = __shfl_xor(jb, off);
            if (odb < db || (odb == db && ojb < jb)) { db = odb; jb = ojb; }
        }
        if (lane == 0) out[(size_t)ZQ_SIZE + gt0] = (float)ja;
        #pragma unroll
        for (int q = 0; q < 4; ++q) {
            int cc = q * 64 + lane;
            out[(size_t)tb0 * CDIM * HW + (size_t)cc * HW + th0] =
                emb[(size_t)ja * CDIM + cc];
        }
        if (gt1 >= 0) {
            if (lane == 0) out[(size_t)ZQ_SIZE + gt1] = (float)jb;
            #pragma unroll
            for (int q = 0; q < 4; ++q) {
                int cc = q * 64 + lane;
                out[(size_t)tb1 * CDIM * HW + (size_t)cc * HW + th1] =
                    emb[(size_t)jb * CDIM + cc];
            }
        }
    }
}

// ---------------- legacy round-1 kernel (only if ws too small) ----------------
#define BM 32
#define BN 256
#define BK 16
__global__ __launch_bounds__(256, 3) void vq_legacy(const float* __restrict__ z,
                                                    const float* __restrict__ emb,
                                                    const float* __restrict__ ee,
                                                    float* __restrict__ out) {
    __shared__ float zs[CDIM][BM];
    __shared__ float es[BK][BN];
    __shared__ float ees[BN];
    __shared__ float zzs[BM];
    __shared__ float red_d[4][BM];
    __shared__ int   red_j[4][BM];
    __shared__ int   bestj_s[BM];

    const int tid = threadIdx.x;
    const int b   = blockIdx.x >> 7;
    const int hw0 = (blockIdx.x & 127) << 5;
    const int ti  = tid & 7;
    const int tj  = tid >> 3;
    const int tm0 = ti << 2;
    const int jc0 = tj << 3;
    {
        const float* zb = z + (size_t)b * CDIM * HW + hw0;
        #pragma unroll
        for (int r = 0; r < 8; ++r) {
            int f4 = (r << 8) + tid;
            int c  = f4 >> 3;
            int t4 = (f4 & 7) << 2;
            float4 v = *reinterpret_cast<const float4*>(zb + (size_t)c * HW + t4);
            *reinterpret_cast<float4*>(&zs[c][t4]) = v;
        }
    }
    __syncthreads();
    if (tid < BM) zzs[tid] = pairwise256_sq([&](int i) { return zs[i][tid]; });
    __syncthreads();
    float bd[4]; int bj[4];
    #pragma unroll
    for (int i = 0; i < 4; ++i) { bd[i] = INFINITY; bj[i] = NE; }
    for (int jt = 0; jt < NE / BN; ++jt) {
        const int j0 = jt * BN;
        float acc[4][8];
        #pragma unroll
        for (int i = 0; i < 4; ++i)
            #pragma unroll
            for (int jj = 0; jj < 8; ++jj) acc[i][jj] = 0.0f;
        for (int kt = 0; kt < CDIM / BK; ++kt) {
            __syncthreads();
            #pragma unroll
            for (int r = 0; r < 4; ++r) {
                int f4 = (r << 8) + tid;
                int jj = f4 >> 2;
                int c4 = (f4 & 3) << 2;
                float4 v = *reinterpret_cast<const float4*>(
                    emb + (size_t)(j0 + jj) * CDIM + kt * BK + c4);
                es[c4 + 0][jj] = v.x; es[c4 + 1][jj] = v.y;
                es[c4 + 2][jj] = v.z; es[c4 + 3][jj] = v.w;
            }
            if (kt == 0 && tid < BN) ees[tid] = ee[j0 + tid];
            __syncthreads();
            #pragma unroll
            for (int k = 0; k < BK; ++k) {
                float4 av  = *reinterpret_cast<const float4*>(&zs[kt * BK + k][tm0]);
                float4 bv0 = *reinterpret_cast<const float4*>(&es[k][jc0]);
                float4 bv1 = *reinterpret_cast<const float4*>(&es[k][jc0 + 4]);
                float bb[8] = {bv0.x, bv0.y, bv0.z, bv0.w, bv1.x, bv1.y, bv1.z, bv1.w};
                #pragma unroll
                for (int jj = 0; jj < 8; ++jj) {
                    acc[0][jj] = fmaf(av.x, bb[jj], acc[0][jj]);
                    acc[1][jj] = fmaf(av.y, bb[jj], acc[1][jj]);
                    acc[2][jj] = fmaf(av.z, bb[jj], acc[2][jj]);
                    acc[3][jj] = fmaf(av.w, bb[jj], acc[3][jj]);
                }
            }
        }
        #pragma unroll
        for (int i = 0; i < 4; ++i) {
            float zzv = zzs[tm0 + i];
            #pragma unroll
            for (int jj = 0; jj < 8; ++jj) {
                float t1 = zzv + ees[jc0 + jj];
                float d  = t1 - 2.0f * acc[i][jj];
                if (d < bd[i]) { bd[i] = d; bj[i] = j0 + jc0 + jj; }
            }
        }
    }
    #pragma unroll
    for (int off = 8; off <= 32; off <<= 1) {
        #pragma unroll
        for (int i = 0; i < 4; ++i) {
            float od = __shfl_xor(bd[i], off);
            int   oj = __shfl_xor(bj[i], off);
            if (od < bd[i] || (od == bd[i] && oj < bj[i])) { bd[i] = od; bj[i] = oj; }
        }
    }
    {
        const int lane = tid & 63;
        const int w    = tid >> 6;
        if (lane < 8) {
            #pragma unroll
            for (int i = 0; i < 4; ++i) {
                red_d[w][lane * 4 + i] = bd[i];
                red_j[w][lane * 4 + i] = bj[i];
            }
        }
    }
    __syncthreads();
    if (tid < BM) {
        float d = red_d[0][tid]; int j = red_j[0][tid];
        #pragma unroll
        for (int w2 = 1; w2 < 4; ++w2) {
            float od = red_d[w2][tid]; int oj = red_j[w2][tid];
            if (od < d || (od == d && oj < j)) { d = od; j = oj; }
        }
        bestj_s[tid] = j;
        out[(size_t)ZQ_SIZE + (size_t)b * HW + hw0 + tid] = (float)j;
    }
    __syncthreads();
    {
        const int t  = tid & 31;
        const int c0 = tid >> 5;
        const int jb = bestj_s[t];
        const float* er = emb + (size_t)jb * CDIM;
        float* ob = out + (size_t)b * CDIM * HW + hw0 + t;
        #pragma unroll
        for (int c = c0; c < CDIM; c += 8) ob[(size_t)c * HW] = er[c];
    }
}

extern "C" void kernel_launch(void* const* d_in, const int* in_sizes, int n_in,
                              void* d_out, int out_size, void* d_ws, size_t ws_size,
                              hipStream_t stream) {
    const float* z   = (const float*)d_in[0];
    const float* emb = (const float*)d_in[1];
    float* out = (float*)d_out;
    char*  ws  = (char*)d_ws;

    float*    ee   = (float*)(ws + WS_EE);
    float*    zzw  = (float*)(ws + WS_ZZ);
    int*      cnt  = (int*)  (ws + WS_CNT);
    int*      list = (int*)  (ws + WS_LIST);
    ushort_t* eswz = (ushort_t*)(ws + WS_ESWZ);

    if (ws_size >= (size_t)WS_NEEDED) {
        ecvt_kernel<<<dim3(132), dim3(256), 0, stream>>>(emb, eswz, ee, cnt);
        vq_main<<<dim3((NB * HW) / 64), dim3(512), 0, stream>>>(z, emb, eswz, ee, zzw,
                                                                cnt, list, out);
        vq_fallback<<<dim3(256), dim3(512), 0, stream>>>(z, emb, ee, zzw, cnt, list, out);
    } else {
        ee_kernel<<<dim3(NE / 256), dim3(256), 0, stream>>>(emb, ee);
        vq_legacy<<<dim3((NB * HW) / BM), dim3(256), 0, stream>>>(z, emb, ee, out);
    }
}